// Round 3
// baseline (833.517 us; speedup 1.0000x reference)
//
#include <hip/hip_runtime.h>
#include <hip/hip_bf16.h>

// Performer (FAVOR+) attention. B=4 H=8 N=4096 D=64 M=256.
// Round-3: K-side (stab + phi_k -> ksum/ctx) rebuilt on MFMA bf16 with
// 3-product hi/lo split (hh+hl+lh, rel err ~3e-5). Frame-0 exp accumulation
// (no stab needed in-pass; exp(-stab) applied in fixup), true max computed
// same-pass via CAS-max. Q-side out_kernel kept verbatim from round 2
// (verified consumer). eps terms are frame-independent: split out via
// per-head Vs (masked V column-sum) and added in fixup.

typedef __attribute__((ext_vector_type(8))) short short8;
typedef __attribute__((ext_vector_type(4))) float floatx4;

constexpr int BB = 4, HH = 8, NN = 4096, DD = 64, MM = 256, BH = 32;
constexpr float SCALE = 0.3535533905932738f;  // 64^-0.25
constexpr float RATIO = 0.0625f;              // 256^-0.5
constexpr float EPSI  = 1e-4f;
constexpr float NEGINF = -3.4e38f;

// round-half-up bf16 split: hi = rnd16(x), lo = x - hi (exact), packed pairs.
__device__ inline unsigned pk2(float a, float b) {
  unsigned ua = __float_as_uint(a) + 0x8000u;
  unsigned ub = __float_as_uint(b) + 0x8000u;
  return (ua >> 16) | (ub & 0xffff0000u);
}
__device__ inline float hif(float x) {
  return __uint_as_float((__float_as_uint(x) + 0x8000u) & 0xffff0000u);
}

union Frag { short8 s8; unsigned u[4]; };

__device__ inline void atomicMaxF(float* a, float v) {
  unsigned* ai = (unsigned*)a;
  unsigned old = __atomic_load_n(ai, __ATOMIC_RELAXED);
  while (__uint_as_float(old) < v) {
    unsigned assumed = old;
    old = atomicCAS(ai, assumed, __float_as_uint(v));
    if (old == assumed) break;
  }
}

// ---------------- vsum: Vs[bh][e] = sum_n mask*V; init stabk ----------------
__global__ __launch_bounds__(256) void vsum_kernel(
    const float* __restrict__ V, const float* __restrict__ mask,
    float* __restrict__ Vs, float* __restrict__ stabk) {
  const int bh = blockIdx.x, b = bh >> 3, t = threadIdx.x;
  const int e = t & 63, g = t >> 6;
  float s = 0.f;
  for (int n = g; n < NN; n += 4)
    s += V[((size_t)bh * NN + n) * DD + e] * mask[b * NN + n];
  __shared__ float red[256];
  red[t] = s;
  __syncthreads();
  if (t < 64) Vs[bh * DD + t] = (red[t] + red[t + 64]) + (red[t + 128] + red[t + 192]);
  if (t == 0) stabk[bh] = NEGINF;
}

// ---------------- kside: MFMA phi_k pass -----------------------------------
// grid (16, 32), 256 thr. Block: 256 K-rows, chunks of 32.
// S1: Xp tile = Ks @ P^T (A=Ks from LDS, B=P persistent regs)
// S2: p = exp(xp - diag) frame-0; running max; ksum partials
// S3: ctx += phi^T @ Vm (A=phi via wave-private frag-ready LDS, B=Vt LDS)
__global__ __launch_bounds__(256) void kside_kernel(
    const float* __restrict__ K, const float* __restrict__ V,
    const float* __restrict__ mask, const float* __restrict__ proj,
    float* __restrict__ stabk, float* __restrict__ ksE,
    float* __restrict__ ctxE) {
  const int bh = blockIdx.y, b = bh >> 3;
  const int t = threadIdx.x;
  const int w = t >> 6, l = t & 63, c = l & 15, sq = l >> 4;
  const int m0 = w * 64;  // this wave's m-range [m0, m0+64)

  __shared__ __align__(16) unsigned short sKs[2][32 * 72];  // [plane][n][d] pad 72
  __shared__ __align__(16) unsigned short sVt[2][64 * 40];  // [plane][e][n] pad 40
  __shared__ float sDiag[32];
  __shared__ float sRed[4];
  __shared__ __align__(16) unsigned short sPhi[4][4][2][512]; // [w][mtile][plane][lane*8]

  // --- persistent B-frags of P^T: [mtile][kstep][plane], from global ---
  Frag Bp[4][2][2];
#pragma unroll
  for (int tt = 0; tt < 4; ++tt)
#pragma unroll
    for (int s = 0; s < 2; ++s) {
      const float* pp = proj + (m0 + tt * 16 + c) * DD + s * 32 + sq * 8;
      float4 x0 = *(const float4*)pp;
      float4 x1 = *(const float4*)(pp + 4);
      float v[8] = {x0.x, x0.y, x0.z, x0.w, x1.x, x1.y, x1.z, x1.w};
#pragma unroll
      for (int j = 0; j < 4; ++j) {
        Bp[tt][s][0].u[j] = pk2(v[2 * j], v[2 * j + 1]);
        float l0 = v[2 * j] - hif(v[2 * j]);
        float l1 = v[2 * j + 1] - hif(v[2 * j + 1]);
        Bp[tt][s][1].u[j] = pk2(l0, l1);
      }
    }

  floatx4 ctxacc[4][4];  // [mtile][etile]
#pragma unroll
  for (int i = 0; i < 4; ++i)
#pragma unroll
    for (int j = 0; j < 4; ++j) ctxacc[i][j] = (floatx4){0.f, 0.f, 0.f, 0.f};
  float ksac[4] = {0.f, 0.f, 0.f, 0.f};
  float mxloc = NEGINF;

  const int r0 = blockIdx.x * 256;

  for (int ch = 0; ch < 8; ++ch) {
    const int rb = r0 + ch * 32;
    __syncthreads();  // protect prior chunk's LDS reads

    // ---- stage Ks (scaled+masked, split) + diag ----
#pragma unroll
    for (int rep = 0; rep < 2; ++rep) {
      const int f = t + rep * 256;
      const int n = f >> 4, dg = f & 15;
      const float mk = mask[b * NN + rb + n];
      const float msc = mk * SCALE;
      float4 kv = *(const float4*)(K + ((size_t)bh * NN + rb + n) * DD + dg * 4);
      float k0 = kv.x * msc, k1 = kv.y * msc, k2 = kv.z * msc, k3 = kv.w * msc;
      float ss = fmaf(k0, k0, fmaf(k1, k1, fmaf(k2, k2, k3 * k3)));
      ss += __shfl_xor(ss, 1); ss += __shfl_xor(ss, 2);
      ss += __shfl_xor(ss, 4); ss += __shfl_xor(ss, 8);
      if (dg == 0) sDiag[n] = 0.5f * ss;
      unsigned h0 = pk2(k0, k1), h1 = pk2(k2, k3);
      float q0 = k0 - hif(k0), q1 = k1 - hif(k1);
      float q2 = k2 - hif(k2), q3 = k3 - hif(k3);
      unsigned lo0 = pk2(q0, q1), lo1 = pk2(q2, q3);
      *(uint2*)(&sKs[0][n * 72 + dg * 4]) = make_uint2(h0, h1);
      *(uint2*)(&sKs[1][n * 72 + dg * 4]) = make_uint2(lo0, lo1);
    }
    // ---- stage Vt (masked, split, transposed) ----
#pragma unroll
    for (int rep = 0; rep < 2; ++rep) {
      const int f = t + rep * 256;
      const int n = f >> 4, eg = f & 15;
      const float mk = mask[b * NN + rb + n];
      float4 vv = *(const float4*)(V + ((size_t)bh * NN + rb + n) * DD + eg * 4);
      float v0 = vv.x * mk, v1 = vv.y * mk, v2 = vv.z * mk, v3 = vv.w * mk;
      float va[4] = {v0, v1, v2, v3};
#pragma unroll
      for (int j = 0; j < 4; ++j) {
        unsigned u = __float_as_uint(va[j]) + 0x8000u;
        sVt[0][(eg * 4 + j) * 40 + n] = (unsigned short)(u >> 16);
        float lo = va[j] - hif(va[j]);
        sVt[1][(eg * 4 + j) * 40 + n] = (unsigned short)((__float_as_uint(lo) + 0x8000u) >> 16);
      }
    }
    __syncthreads();

    // ---- S1: Xp = Ks @ P^T ----
    Frag Ak[2][2][2];  // [ntile][kstep][plane]
#pragma unroll
    for (int i = 0; i < 2; ++i)
#pragma unroll
      for (int s = 0; s < 2; ++s) {
        Ak[i][s][0].s8 = *(const short8*)&sKs[0][(i * 16 + c) * 72 + s * 32 + sq * 8];
        Ak[i][s][1].s8 = *(const short8*)&sKs[1][(i * 16 + c) * 72 + s * 32 + sq * 8];
      }
    floatx4 xacc[2][4];
#pragma unroll
    for (int i = 0; i < 2; ++i)
#pragma unroll
      for (int tt = 0; tt < 4; ++tt) {
        floatx4 a = (floatx4){0.f, 0.f, 0.f, 0.f};
#pragma unroll
        for (int s = 0; s < 2; ++s) {
          a = __builtin_amdgcn_mfma_f32_16x16x32_bf16(Ak[i][s][0].s8, Bp[tt][s][0].s8, a, 0, 0, 0);
          a = __builtin_amdgcn_mfma_f32_16x16x32_bf16(Ak[i][s][0].s8, Bp[tt][s][1].s8, a, 0, 0, 0);
          a = __builtin_amdgcn_mfma_f32_16x16x32_bf16(Ak[i][s][1].s8, Bp[tt][s][0].s8, a, 0, 0, 0);
        }
        xacc[i][tt] = a;
      }

    // ---- S2: exp frame-0, max, ksum partials, phi scatter (wave-local) ----
    float dg8[2][4];
#pragma unroll
    for (int i = 0; i < 2; ++i)
#pragma unroll
      for (int jj = 0; jj < 4; ++jj) dg8[i][jj] = sDiag[i * 16 + sq * 4 + jj];

    const int qp_c = (sq >> 1);     // phi target quad contribution from sq
    const int half = (sq & 1) * 4;  // short offset within target lane
#pragma unroll
    for (int i = 0; i < 2; ++i)
#pragma unroll
      for (int tt = 0; tt < 4; ++tt) {
        float p[4];
#pragma unroll
        for (int jj = 0; jj < 4; ++jj) {
          float xp = xacc[i][tt][jj];
          mxloc = fmaxf(mxloc, xp);
          p[jj] = __expf(xp - dg8[i][jj]);
          ksac[tt] += p[jj];
        }
        unsigned h0 = pk2(p[0], p[1]), h1 = pk2(p[2], p[3]);
        float q0 = p[0] - hif(p[0]), q1 = p[1] - hif(p[1]);
        float q2 = p[2] - hif(p[2]), q3 = p[3] - hif(p[3]);
        unsigned lo0 = pk2(q0, q1), lo1 = pk2(q2, q3);
        const int tl = (i * 2 + qp_c) * 16 + c;  // target lane
        *(uint2*)(&sPhi[w][tt][0][tl * 8 + half]) = make_uint2(h0, h1);
        *(uint2*)(&sPhi[w][tt][1][tl * 8 + half]) = make_uint2(lo0, lo1);
      }

    // ---- S3: ctx += phi^T @ Vm ----
    Frag Bv[4][2];
#pragma unroll
    for (int E = 0; E < 4; ++E) {
      Bv[E][0].s8 = *(const short8*)&sVt[0][(E * 16 + c) * 40 + sq * 8];
      Bv[E][1].s8 = *(const short8*)&sVt[1][(E * 16 + c) * 40 + sq * 8];
    }
#pragma unroll
    for (int tt = 0; tt < 4; ++tt) {
      Frag Ap[2];
      Ap[0].s8 = *(const short8*)&sPhi[w][tt][0][l * 8];
      Ap[1].s8 = *(const short8*)&sPhi[w][tt][1][l * 8];
#pragma unroll
      for (int E = 0; E < 4; ++E) {
        ctxacc[tt][E] = __builtin_amdgcn_mfma_f32_16x16x32_bf16(Ap[0].s8, Bv[E][0].s8, ctxacc[tt][E], 0, 0, 0);
        ctxacc[tt][E] = __builtin_amdgcn_mfma_f32_16x16x32_bf16(Ap[0].s8, Bv[E][1].s8, ctxacc[tt][E], 0, 0, 0);
        ctxacc[tt][E] = __builtin_amdgcn_mfma_f32_16x16x32_bf16(Ap[1].s8, Bv[E][0].s8, ctxacc[tt][E], 0, 0, 0);
      }
    }
  }

  // ---- epilogue: ksum partials, global max, ctx atomics ----
#pragma unroll
  for (int tt = 0; tt < 4; ++tt) {
    float v = ksac[tt];
    v += __shfl_xor(v, 16);
    v += __shfl_xor(v, 32);
    if (sq == 0) atomicAdd(&ksE[bh * MM + m0 + tt * 16 + c], v);
  }
#pragma unroll
  for (int off = 1; off <= 32; off <<= 1) mxloc = fmaxf(mxloc, __shfl_xor(mxloc, off));
  if (l == 0) sRed[w] = mxloc;
  __syncthreads();
  if (t == 0)
    atomicMaxF(&stabk[bh], fmaxf(fmaxf(sRed[0], sRed[1]), fmaxf(sRed[2], sRed[3])));

  float* cg = ctxE + (size_t)bh * MM * DD;
#pragma unroll
  for (int tt = 0; tt < 4; ++tt)
#pragma unroll
    for (int E = 0; E < 4; ++E) {
#pragma unroll
      for (int r = 0; r < 4; ++r) {
        const int m = m0 + tt * 16 + sq * 4 + r;
        const int e = E * 16 + c;
        atomicAdd(&cg[m * DD + e], ctxacc[tt][E][r]);
      }
    }
}

// ---------------- fixup: finalize ksum, ctx with exp(-stab) + eps ----------
__global__ __launch_bounds__(256) void fixup_kernel(
    const float* __restrict__ stabk, const float* __restrict__ Vs,
    const float* __restrict__ ksE, float* __restrict__ ctx,
    float* __restrict__ ksum) {
  const int bh = blockIdx.x, t = threadIdx.x;
  const float es = __expf(-stabk[bh]);
  ksum[bh * MM + t] = RATIO * (es * ksE[bh * MM + t] + (float)NN * EPSI);
  float* cg = ctx + (size_t)bh * MM * DD;
  const float* vs = Vs + bh * DD;
  for (int i = t; i < MM * DD; i += 256)
    cg[i] = RATIO * (es * cg[i] + EPSI * vs[i & 63]);
}

// ---------------- headsum (round-2 verbatim) -------------------------------
__global__ __launch_bounds__(256) void headsum_kernel(
    const float* __restrict__ ksum, const float* __restrict__ ctx,
    float* __restrict__ kssum, float* __restrict__ ctxsum) {
  const int bh = blockIdx.x, t = threadIdx.x;
  const int e = t & 63, q = t >> 6;
  __shared__ float red[256];

  const float* cb = ctx + (size_t)bh * MM * DD;
  float s = 0.f;
  for (int m = q * 64; m < q * 64 + 64; ++m) s += cb[m * DD + e];
  red[t] = s;
  __syncthreads();
  if (t < 64) ctxsum[bh * DD + t] = (red[t] + red[t + 64]) + (red[t + 128] + red[t + 192]);
  float kv = ksum[bh * MM + t];
  __syncthreads();
  red[t] = kv;
  __syncthreads();
  for (int off = 128; off >= 1; off >>= 1) {
    if (t < off) red[t] += red[t + off];
    __syncthreads();
  }
  if (t == 0) kssum[bh] = red[0];
}

// ---------------- out_kernel (round-2 verbatim) ----------------------------
__global__ __launch_bounds__(256) void out_kernel(
    const float* __restrict__ Q, const float* __restrict__ proj,
    const float* __restrict__ ksum, const float* __restrict__ ctx,
    const float* __restrict__ kssum, const float* __restrict__ ctxsum,
    float* __restrict__ out) {
  const int bh = blockIdx.y;
  const int t  = threadIdx.x;
  const int row = blockIdx.x * 256 + t;

  __shared__ float ldsP[64 * DD];
  __shared__ float ldsC[64 * DD];
  __shared__ float ldsS[64];

  float4 q[16];
  {
    const float4* qr = (const float4*)(Q + ((size_t)bh * NN + row) * DD);
#pragma unroll
    for (int i = 0; i < 16; ++i) q[i] = qr[i];
  }
  float s0 = 0, s1 = 0, s2 = 0, s3 = 0;
#pragma unroll
  for (int i = 0; i < 16; ++i) {
    q[i].x *= SCALE; q[i].y *= SCALE; q[i].z *= SCALE; q[i].w *= SCALE;
    s0 = fmaf(q[i].x, q[i].x, s0); s1 = fmaf(q[i].y, q[i].y, s1);
    s2 = fmaf(q[i].z, q[i].z, s2); s3 = fmaf(q[i].w, q[i].w, s3);
  }
  const float diag = 0.5f * ((s0 + s1) + (s2 + s3));

  float4 o[16];
#pragma unroll
  for (int i = 0; i < 16; ++i) o[i] = make_float4(0.f, 0.f, 0.f, 0.f);
  float dsum = 0.f;
  float F = 0.f;
  float M = NEGINF;

  const float* cb = ctx + (size_t)bh * MM * DD;
  const float* kb = ksum + bh * MM;

  for (int ch = 0; ch < 4; ++ch) {
    __syncthreads();
    const float4* ps = (const float4*)(proj + ch * 64 * DD);
    const float4* cs = (const float4*)(cb + ch * 64 * DD);
    float4* pd = (float4*)ldsP;
    float4* cd = (float4*)ldsC;
#pragma unroll
    for (int i = 0; i < 4; ++i) {
      pd[t + i * 256] = ps[t + i * 256];
      cd[t + i * 256] = cs[t + i * 256];
    }
    if (t < 64) ldsS[t] = kb[ch * 64 + t];
    __syncthreads();

    float cmax = NEGINF;
    for (int mm = 0; mm < 64; ++mm) {
      const float4* pm = (const float4*)(ldsP + mm * DD);
      float a0 = 0, a1 = 0, a2 = 0, a3 = 0;
#pragma unroll
      for (int i = 0; i < 16; ++i) {
        float4 pp = pm[i];
        a0 = fmaf(q[i].x, pp.x, a0); a1 = fmaf(q[i].y, pp.y, a1);
        a2 = fmaf(q[i].z, pp.z, a2); a3 = fmaf(q[i].w, pp.w, a3);
      }
      const float xp = (a0 + a1) + (a2 + a3);
      cmax = fmaxf(cmax, xp);
      const float p = __expf(xp - diag - F);
      dsum = fmaf(p, ldsS[mm], dsum);
      const float4* cm = (const float4*)(ldsC + mm * DD);
#pragma unroll
      for (int i = 0; i < 16; ++i) {
        float4 cc = cm[i];
        o[i].x = fmaf(p, cc.x, o[i].x);
        o[i].y = fmaf(p, cc.y, o[i].y);
        o[i].z = fmaf(p, cc.z, o[i].z);
        o[i].w = fmaf(p, cc.w, o[i].w);
      }
    }
    M = fmaxf(M, cmax);
    const float fac = __expf(F - M);
    F = M;
    dsum *= fac;
#pragma unroll
    for (int i = 0; i < 16; ++i) {
      o[i].x *= fac; o[i].y *= fac; o[i].z *= fac; o[i].w *= fac;
    }
  }

  const float dinv = 1.f / (dsum + EPSI * kssum[bh]);
  const float4* csb = (const float4*)(ctxsum + bh * DD);
  float4* orow = (float4*)(out + ((size_t)bh * NN + row) * DD);
#pragma unroll
  for (int i = 0; i < 16; ++i) {
    float4 cs = csb[i];
    float4 r;
    r.x = (o[i].x + EPSI * cs.x) * dinv;
    r.y = (o[i].y + EPSI * cs.y) * dinv;
    r.z = (o[i].z + EPSI * cs.z) * dinv;
    r.w = (o[i].w + EPSI * cs.w) * dinv;
    orow[i] = r;
  }
}

extern "C" void kernel_launch(void* const* d_in, const int* in_sizes, int n_in,
                              void* d_out, int out_size, void* d_ws, size_t ws_size,
                              hipStream_t stream) {
  const float* Q    = (const float*)d_in[0];
  const float* K    = (const float*)d_in[1];
  const float* V    = (const float*)d_in[2];
  const float* mask = (const float*)d_in[3];
  const float* proj = (const float*)d_in[4];
  float* out = (float*)d_out;

  float* wsf    = (float*)d_ws;
  float* stabk  = wsf;            // 32
  float* Vs     = wsf + 32;       // 2048
  float* kssum  = wsf + 4096;     // 32
  float* ctxsum = wsf + 4128;     // 2048
  float* ksum   = wsf + 8192;     // 8192
  float* ksE    = wsf + 16384;    // 8192
  float* ctx    = wsf + 24576;    // 524288 -> end 548864 floats (~2.1 MB)

  // zero ksE + ctx (accumulated via atomics)
  hipMemsetAsync(wsf + 16384, 0, (8192 + 524288) * sizeof(float), stream);

  vsum_kernel<<<BH, 256, 0, stream>>>(V, mask, Vs, stabk);
  kside_kernel<<<dim3(16, BH), 256, 0, stream>>>(K, V, mask, proj, stabk, ksE, ctx);
  fixup_kernel<<<BH, 256, 0, stream>>>(stabk, Vs, ksE, ctx, ksum);
  headsum_kernel<<<BH, 256, 0, stream>>>(ksum, ctx, kssum, ctxsum);
  out_kernel<<<dim3(16, BH), 256, 0, stream>>>(Q, proj, ksum, ctx, kssum, ctxsum, out);
}

// Round 4
// 279.769 us; speedup vs baseline: 2.9793x; 2.9793x over previous
//
#include <hip/hip_runtime.h>
#include <hip/hip_bf16.h>

// Performer (FAVOR+) attention. B=4 H=8 N=4096 D=64 M=256.
// Round-4:
//  - vsum: was latency-bound (32 blocks, 460us). Now 1024 blocks + atomics (~10us).
//  - out_kernel rebuilt on MFMA bf16 3-product split (kside-validated machinery).
//    GEMM1: xp tile = proj @ Q^T  (D[m][qrow]) -> frame-0 exp, row-max in regs.
//    GEMM2: out = p @ ctxT (ctxT pre-split to bf16 hi/lo planes in fixup).
//    eps terms applied at store: (A0 + e^s*eps*ctxsum)/(D0 + e^s*eps*kssum).
//  - fixup also emits ctxT split planes + ctxsum/kssum (headsum folded in).
//  - kside kept verbatim from round 3 (validated).

typedef __attribute__((ext_vector_type(8))) short short8;
typedef __attribute__((ext_vector_type(4))) float floatx4;

constexpr int BB = 4, HH = 8, NN = 4096, DD = 64, MM = 256, BH = 32;
constexpr float SCALE = 0.3535533905932738f;  // 64^-0.25
constexpr float RATIO = 0.0625f;              // 256^-0.5
constexpr float EPSI  = 1e-4f;
constexpr float NEGINF = -3.4e38f;

__device__ inline unsigned pk2(float a, float b) {
  unsigned ua = __float_as_uint(a) + 0x8000u;
  unsigned ub = __float_as_uint(b) + 0x8000u;
  return (ua >> 16) | (ub & 0xffff0000u);
}
__device__ inline float hif(float x) {
  return __uint_as_float((__float_as_uint(x) + 0x8000u) & 0xffff0000u);
}
__device__ inline unsigned short bhi(float x) {
  return (unsigned short)((__float_as_uint(x) + 0x8000u) >> 16);
}

union Frag { short8 s8; unsigned u[4]; };

__device__ inline void atomicMaxF(float* a, float v) {
  unsigned* ai = (unsigned*)a;
  unsigned old = __atomic_load_n(ai, __ATOMIC_RELAXED);
  while (__uint_as_float(old) < v) {
    unsigned assumed = old;
    old = atomicCAS(ai, assumed, __float_as_uint(v));
    if (old == assumed) break;
  }
}

// ---------------- prep: split proj to bf16 planes; init stabk --------------
__global__ __launch_bounds__(256) void prep_kernel(
    const float* __restrict__ proj, unsigned short* __restrict__ projH,
    unsigned short* __restrict__ projL, float* __restrict__ stabk) {
  const int i = blockIdx.x * 256 + threadIdx.x;  // 16384 elems
  float v = proj[i];
  projH[i] = bhi(v);
  projL[i] = bhi(v - hif(v));
  if (i < BH) stabk[i] = NEGINF;
}

// ---------------- vsum: Vs[bh][e] += sum_n mask*V (1024 blocks) ------------
__global__ __launch_bounds__(256) void vsum_kernel(
    const float* __restrict__ V, const float* __restrict__ mask,
    float* __restrict__ Vs) {
  const int bh = blockIdx.y, b = bh >> 3, t = threadIdx.x;
  const int e = t & 63, g = t >> 6;
  const int n0 = blockIdx.x * 128;
  float s = 0.f;
  for (int n = n0 + g; n < n0 + 128; n += 4)
    s += V[((size_t)bh * NN + n) * DD + e] * mask[b * NN + n];
  __shared__ float red[256];
  red[t] = s;
  __syncthreads();
  if (t < 64)
    atomicAdd(&Vs[bh * DD + t], (red[t] + red[t + 64]) + (red[t + 128] + red[t + 192]));
}

// ---------------- kside: MFMA phi_k pass (round-3 verbatim) ----------------
__global__ __launch_bounds__(256) void kside_kernel(
    const float* __restrict__ K, const float* __restrict__ V,
    const float* __restrict__ mask, const float* __restrict__ proj,
    float* __restrict__ stabk, float* __restrict__ ksE,
    float* __restrict__ ctxE) {
  const int bh = blockIdx.y, b = bh >> 3;
  const int t = threadIdx.x;
  const int w = t >> 6, l = t & 63, c = l & 15, sq = l >> 4;
  const int m0 = w * 64;

  __shared__ __align__(16) unsigned short sKs[2][32 * 72];
  __shared__ __align__(16) unsigned short sVt[2][64 * 40];
  __shared__ float sDiag[32];
  __shared__ float sRed[4];
  __shared__ __align__(16) unsigned short sPhi[4][4][2][512];

  Frag Bp[4][2][2];
#pragma unroll
  for (int tt = 0; tt < 4; ++tt)
#pragma unroll
    for (int s = 0; s < 2; ++s) {
      const float* pp = proj + (m0 + tt * 16 + c) * DD + s * 32 + sq * 8;
      float4 x0 = *(const float4*)pp;
      float4 x1 = *(const float4*)(pp + 4);
      float v[8] = {x0.x, x0.y, x0.z, x0.w, x1.x, x1.y, x1.z, x1.w};
#pragma unroll
      for (int j = 0; j < 4; ++j) {
        Bp[tt][s][0].u[j] = pk2(v[2 * j], v[2 * j + 1]);
        float l0 = v[2 * j] - hif(v[2 * j]);
        float l1 = v[2 * j + 1] - hif(v[2 * j + 1]);
        Bp[tt][s][1].u[j] = pk2(l0, l1);
      }
    }

  floatx4 ctxacc[4][4];
#pragma unroll
  for (int i = 0; i < 4; ++i)
#pragma unroll
    for (int j = 0; j < 4; ++j) ctxacc[i][j] = (floatx4){0.f, 0.f, 0.f, 0.f};
  float ksac[4] = {0.f, 0.f, 0.f, 0.f};
  float mxloc = NEGINF;

  const int r0 = blockIdx.x * 256;

  for (int ch = 0; ch < 8; ++ch) {
    const int rb = r0 + ch * 32;
    __syncthreads();

#pragma unroll
    for (int rep = 0; rep < 2; ++rep) {
      const int f = t + rep * 256;
      const int n = f >> 4, dg = f & 15;
      const float mk = mask[b * NN + rb + n];
      const float msc = mk * SCALE;
      float4 kv = *(const float4*)(K + ((size_t)bh * NN + rb + n) * DD + dg * 4);
      float k0 = kv.x * msc, k1 = kv.y * msc, k2 = kv.z * msc, k3 = kv.w * msc;
      float ss = fmaf(k0, k0, fmaf(k1, k1, fmaf(k2, k2, k3 * k3)));
      ss += __shfl_xor(ss, 1); ss += __shfl_xor(ss, 2);
      ss += __shfl_xor(ss, 4); ss += __shfl_xor(ss, 8);
      if (dg == 0) sDiag[n] = 0.5f * ss;
      unsigned h0 = pk2(k0, k1), h1 = pk2(k2, k3);
      float q0 = k0 - hif(k0), q1 = k1 - hif(k1);
      float q2 = k2 - hif(k2), q3 = k3 - hif(k3);
      unsigned lo0 = pk2(q0, q1), lo1 = pk2(q2, q3);
      *(uint2*)(&sKs[0][n * 72 + dg * 4]) = make_uint2(h0, h1);
      *(uint2*)(&sKs[1][n * 72 + dg * 4]) = make_uint2(lo0, lo1);
    }
#pragma unroll
    for (int rep = 0; rep < 2; ++rep) {
      const int f = t + rep * 256;
      const int n = f >> 4, eg = f & 15;
      const float mk = mask[b * NN + rb + n];
      float4 vv = *(const float4*)(V + ((size_t)bh * NN + rb + n) * DD + eg * 4);
      float va[4] = {vv.x * mk, vv.y * mk, vv.z * mk, vv.w * mk};
#pragma unroll
      for (int j = 0; j < 4; ++j) {
        sVt[0][(eg * 4 + j) * 40 + n] = bhi(va[j]);
        sVt[1][(eg * 4 + j) * 40 + n] = bhi(va[j] - hif(va[j]));
      }
    }
    __syncthreads();

    Frag Ak[2][2][2];
#pragma unroll
    for (int i = 0; i < 2; ++i)
#pragma unroll
      for (int s = 0; s < 2; ++s) {
        Ak[i][s][0].s8 = *(const short8*)&sKs[0][(i * 16 + c) * 72 + s * 32 + sq * 8];
        Ak[i][s][1].s8 = *(const short8*)&sKs[1][(i * 16 + c) * 72 + s * 32 + sq * 8];
      }
    floatx4 xacc[2][4];
#pragma unroll
    for (int i = 0; i < 2; ++i)
#pragma unroll
      for (int tt = 0; tt < 4; ++tt) {
        floatx4 a = (floatx4){0.f, 0.f, 0.f, 0.f};
#pragma unroll
        for (int s = 0; s < 2; ++s) {
          a = __builtin_amdgcn_mfma_f32_16x16x32_bf16(Ak[i][s][0].s8, Bp[tt][s][0].s8, a, 0, 0, 0);
          a = __builtin_amdgcn_mfma_f32_16x16x32_bf16(Ak[i][s][0].s8, Bp[tt][s][1].s8, a, 0, 0, 0);
          a = __builtin_amdgcn_mfma_f32_16x16x32_bf16(Ak[i][s][1].s8, Bp[tt][s][0].s8, a, 0, 0, 0);
        }
        xacc[i][tt] = a;
      }

    float dg8[2][4];
#pragma unroll
    for (int i = 0; i < 2; ++i)
#pragma unroll
      for (int jj = 0; jj < 4; ++jj) dg8[i][jj] = sDiag[i * 16 + sq * 4 + jj];

    const int qp_c = (sq >> 1);
    const int half = (sq & 1) * 4;
#pragma unroll
    for (int i = 0; i < 2; ++i)
#pragma unroll
      for (int tt = 0; tt < 4; ++tt) {
        float p[4];
#pragma unroll
        for (int jj = 0; jj < 4; ++jj) {
          float xp = xacc[i][tt][jj];
          mxloc = fmaxf(mxloc, xp);
          p[jj] = __expf(xp - dg8[i][jj]);
          ksac[tt] += p[jj];
        }
        unsigned h0 = pk2(p[0], p[1]), h1 = pk2(p[2], p[3]);
        float q0 = p[0] - hif(p[0]), q1 = p[1] - hif(p[1]);
        float q2 = p[2] - hif(p[2]), q3 = p[3] - hif(p[3]);
        unsigned lo0 = pk2(q0, q1), lo1 = pk2(q2, q3);
        const int tl = (i * 2 + qp_c) * 16 + c;
        *(uint2*)(&sPhi[w][tt][0][tl * 8 + half]) = make_uint2(h0, h1);
        *(uint2*)(&sPhi[w][tt][1][tl * 8 + half]) = make_uint2(lo0, lo1);
      }

    Frag Bv[4][2];
#pragma unroll
    for (int E = 0; E < 4; ++E) {
      Bv[E][0].s8 = *(const short8*)&sVt[0][(E * 16 + c) * 40 + sq * 8];
      Bv[E][1].s8 = *(const short8*)&sVt[1][(E * 16 + c) * 40 + sq * 8];
    }
#pragma unroll
    for (int tt = 0; tt < 4; ++tt) {
      Frag Ap[2];
      Ap[0].s8 = *(const short8*)&sPhi[w][tt][0][l * 8];
      Ap[1].s8 = *(const short8*)&sPhi[w][tt][1][l * 8];
#pragma unroll
      for (int E = 0; E < 4; ++E) {
        ctxacc[tt][E] = __builtin_amdgcn_mfma_f32_16x16x32_bf16(Ap[0].s8, Bv[E][0].s8, ctxacc[tt][E], 0, 0, 0);
        ctxacc[tt][E] = __builtin_amdgcn_mfma_f32_16x16x32_bf16(Ap[0].s8, Bv[E][1].s8, ctxacc[tt][E], 0, 0, 0);
        ctxacc[tt][E] = __builtin_amdgcn_mfma_f32_16x16x32_bf16(Ap[1].s8, Bv[E][0].s8, ctxacc[tt][E], 0, 0, 0);
      }
    }
  }

#pragma unroll
  for (int tt = 0; tt < 4; ++tt) {
    float v = ksac[tt];
    v += __shfl_xor(v, 16);
    v += __shfl_xor(v, 32);
    if (sq == 0) atomicAdd(&ksE[bh * MM + m0 + tt * 16 + c], v);
  }
#pragma unroll
  for (int off = 1; off <= 32; off <<= 1) mxloc = fmaxf(mxloc, __shfl_xor(mxloc, off));
  if (l == 0) sRed[w] = mxloc;
  __syncthreads();
  if (t == 0)
    atomicMaxF(&stabk[bh], fmaxf(fmaxf(sRed[0], sRed[1]), fmaxf(sRed[2], sRed[3])));

  float* cg = ctxE + (size_t)bh * MM * DD;
#pragma unroll
  for (int tt = 0; tt < 4; ++tt)
#pragma unroll
    for (int E = 0; E < 4; ++E) {
#pragma unroll
      for (int r = 0; r < 4; ++r) {
        const int m = m0 + tt * 16 + sq * 4 + r;
        const int e = E * 16 + c;
        atomicAdd(&cg[m * DD + e], ctxacc[tt][E][r]);
      }
    }
}

// ---------------- fixup: finalize ksum/ctx; emit ctxT splits + sums --------
__global__ __launch_bounds__(256) void fixup_kernel(
    const float* __restrict__ stabk, const float* __restrict__ Vs,
    const float* __restrict__ ksE, const float* __restrict__ ctxE,
    float* __restrict__ ksum, float* __restrict__ kssum,
    float* __restrict__ ctxsum, unsigned short* __restrict__ ctxTH,
    unsigned short* __restrict__ ctxTL) {
  const int bh = blockIdx.x, t = threadIdx.x;
  const float es = __expf(-stabk[bh]);
  __shared__ float red[256];

  const float kv = RATIO * (es * ksE[bh * MM + t] + (float)NN * EPSI);
  ksum[bh * MM + t] = kv;
  red[t] = kv;
  __syncthreads();
  for (int off = 128; off >= 1; off >>= 1) {
    if (t < off) red[t] += red[t + off];
    __syncthreads();
  }
  if (t == 0) kssum[bh] = red[0];
  __syncthreads();

  const int e = t & 63, g = t >> 6;
  const float vse = EPSI * Vs[bh * DD + e];
  float cs = 0.f;
  for (int m = g; m < MM; m += 4) {
    float v = RATIO * (es * ctxE[((size_t)bh * MM + m) * DD + e] + vse);
    cs += v;
    ctxTH[((size_t)bh * DD + e) * MM + m] = bhi(v);
    ctxTL[((size_t)bh * DD + e) * MM + m] = bhi(v - hif(v));
  }
  red[t] = cs;
  __syncthreads();
  if (t < 64)
    ctxsum[bh * DD + t] = (red[t] + red[t + 64]) + (red[t + 128] + red[t + 192]);
}

// ---------------- out: MFMA Q side ----------------------------------------
// Block: 64 Q rows (wave w -> 16 rows). Chunks of 64 m.
// GEMM1: D[m][qrow] = proj @ Qs^T  (A=proj chunk from LDS, B=Qs persistent)
// S2: p = exp(xp - diag) frame-0; row-max + dsum in regs; phi -> wave-private
//     frag-ready LDS (kside's contiguous 4-short pattern).
// GEMM2: D[qrow][e] += p @ ctxT   (B=ctxT chunk from LDS)
__global__ __launch_bounds__(256, 2) void out_kernel(
    const float* __restrict__ Q,
    const unsigned short* __restrict__ projH, const unsigned short* __restrict__ projL,
    const float* __restrict__ ksum,
    const unsigned short* __restrict__ ctxTH, const unsigned short* __restrict__ ctxTL,
    const float* __restrict__ kssum, const float* __restrict__ ctxsum,
    float* __restrict__ out) {
  const int bh = blockIdx.y;
  const int r0 = blockIdx.x * 64;
  const int t = threadIdx.x, w = t >> 6, l = t & 63, c = l & 15, sq = l >> 4;

  __shared__ __align__(16) unsigned short sQ[2][64 * 80];
  __shared__ __align__(16) unsigned short sP[2][64 * 80];
  __shared__ __align__(16) unsigned short sC[2][64 * 80];
  __shared__ float sKs[256];
  __shared__ float sDiag[64];
  __shared__ __align__(16) unsigned short sPhi[4][2][2][512];

  // ---- stage Q (scaled, split) + diag; ksum ----
  {
    const int row = t >> 2, q4 = t & 3;
    const float* qp = Q + ((size_t)bh * NN + r0 + row) * DD + q4 * 16;
    float4 t0 = *(const float4*)(qp + 0), t1 = *(const float4*)(qp + 4),
           t2 = *(const float4*)(qp + 8), t3 = *(const float4*)(qp + 12);
    float v[16] = {t0.x, t0.y, t0.z, t0.w, t1.x, t1.y, t1.z, t1.w,
                   t2.x, t2.y, t2.z, t2.w, t3.x, t3.y, t3.z, t3.w};
    float ss = 0.f;
#pragma unroll
    for (int j = 0; j < 16; ++j) { v[j] *= SCALE; ss = fmaf(v[j], v[j], ss); }
    ss += __shfl_xor(ss, 1);
    ss += __shfl_xor(ss, 2);
    if (q4 == 0) sDiag[row] = 0.5f * ss;
    unsigned short* dh = &sQ[0][row * 80 + q4 * 16];
    unsigned short* dl = &sQ[1][row * 80 + q4 * 16];
#pragma unroll
    for (int j = 0; j < 8; ++j) {
      *(unsigned*)&dh[2 * j] = pk2(v[2 * j], v[2 * j + 1]);
      float l0 = v[2 * j] - hif(v[2 * j]), l1 = v[2 * j + 1] - hif(v[2 * j + 1]);
      *(unsigned*)&dl[2 * j] = pk2(l0, l1);
    }
  }
  sKs[t] = ksum[bh * MM + t];
  __syncthreads();

  Frag Bq[2][2];
#pragma unroll
  for (int s = 0; s < 2; ++s)
#pragma unroll
    for (int p = 0; p < 2; ++p)
      Bq[s][p].s8 = *(const short8*)&sQ[p][(w * 16 + c) * 80 + s * 32 + sq * 8];

  const float diagc = sDiag[w * 16 + c];
  floatx4 oacc[4];
#pragma unroll
  for (int E = 0; E < 4; ++E) oacc[E] = (floatx4){0.f, 0.f, 0.f, 0.f};
  float mxacc = NEGINF, dsacc = 0.f;

  for (int mc = 0; mc < 4; ++mc) {
    __syncthreads();
    // ---- stage proj + ctxT chunk (hi/lo) ----
    {
      const int row = t >> 2, q4 = t & 3;
      const size_t gp = (size_t)(mc * 64 + row) * DD + q4 * 16;
      const uint4* ph = (const uint4*)&projH[gp];
      const uint4* pl = (const uint4*)&projL[gp];
      *(uint4*)&sP[0][row * 80 + q4 * 16] = ph[0];
      *(uint4*)&sP[0][row * 80 + q4 * 16 + 8] = ph[1];
      *(uint4*)&sP[1][row * 80 + q4 * 16] = pl[0];
      *(uint4*)&sP[1][row * 80 + q4 * 16 + 8] = pl[1];
      const size_t gc = ((size_t)bh * DD + row) * MM + mc * 64 + q4 * 16;
      const uint4* ch = (const uint4*)&ctxTH[gc];
      const uint4* cl = (const uint4*)&ctxTL[gc];
      *(uint4*)&sC[0][row * 80 + q4 * 16] = ch[0];
      *(uint4*)&sC[0][row * 80 + q4 * 16 + 8] = ch[1];
      *(uint4*)&sC[1][row * 80 + q4 * 16] = cl[0];
      *(uint4*)&sC[1][row * 80 + q4 * 16 + 8] = cl[1];
    }
    __syncthreads();

    // ---- GEMM1 + S2 ----
#pragma unroll
    for (int tt = 0; tt < 4; ++tt) {
      Frag Af[2][2];
#pragma unroll
      for (int s = 0; s < 2; ++s)
#pragma unroll
        for (int p = 0; p < 2; ++p)
          Af[s][p].s8 = *(const short8*)&sP[p][(tt * 16 + c) * 80 + s * 32 + sq * 8];
      floatx4 x = (floatx4){0.f, 0.f, 0.f, 0.f};
#pragma unroll
      for (int s = 0; s < 2; ++s) {
        x = __builtin_amdgcn_mfma_f32_16x16x32_bf16(Af[s][0].s8, Bq[s][0].s8, x, 0, 0, 0);
        x = __builtin_amdgcn_mfma_f32_16x16x32_bf16(Af[s][0].s8, Bq[s][1].s8, x, 0, 0, 0);
        x = __builtin_amdgcn_mfma_f32_16x16x32_bf16(Af[s][1].s8, Bq[s][0].s8, x, 0, 0, 0);
      }
      float p4[4];
#pragma unroll
      for (int jj = 0; jj < 4; ++jj) {
        const float xp = x[jj];
        mxacc = fmaxf(mxacc, xp);
        p4[jj] = __expf(xp - diagc);
        dsacc = fmaf(p4[jj], sKs[mc * 64 + tt * 16 + sq * 4 + jj], dsacc);
      }
      const int kstep = tt >> 1;
      const int tl = ((tt & 1) * 2 + (sq >> 1)) * 16 + c;
      const int off = (sq & 1) * 4;
      float l0 = p4[0] - hif(p4[0]), l1 = p4[1] - hif(p4[1]);
      float l2 = p4[2] - hif(p4[2]), l3 = p4[3] - hif(p4[3]);
      *(uint2*)&sPhi[w][0][kstep][tl * 8 + off] = make_uint2(pk2(p4[0], p4[1]), pk2(p4[2], p4[3]));
      *(uint2*)&sPhi[w][1][kstep][tl * 8 + off] = make_uint2(pk2(l0, l1), pk2(l2, l3));
    }

    // ---- GEMM2 ----
#pragma unroll
    for (int ks = 0; ks < 2; ++ks) {
      Frag Aph[2];
      Aph[0].s8 = *(const short8*)&sPhi[w][0][ks][l * 8];
      Aph[1].s8 = *(const short8*)&sPhi[w][1][ks][l * 8];
#pragma unroll
      for (int E = 0; E < 4; ++E) {
        Frag Bc0, Bc1;
        Bc0.s8 = *(const short8*)&sC[0][(E * 16 + c) * 80 + ks * 32 + sq * 8];
        Bc1.s8 = *(const short8*)&sC[1][(E * 16 + c) * 80 + ks * 32 + sq * 8];
        oacc[E] = __builtin_amdgcn_mfma_f32_16x16x32_bf16(Aph[0].s8, Bc0.s8, oacc[E], 0, 0, 0);
        oacc[E] = __builtin_amdgcn_mfma_f32_16x16x32_bf16(Aph[0].s8, Bc1.s8, oacc[E], 0, 0, 0);
        oacc[E] = __builtin_amdgcn_mfma_f32_16x16x32_bf16(Aph[1].s8, Bc0.s8, oacc[E], 0, 0, 0);
      }
    }
  }

  // ---- reductions + store ----
  mxacc = fmaxf(mxacc, __shfl_xor(mxacc, 16));
  mxacc = fmaxf(mxacc, __shfl_xor(mxacc, 32));
  dsacc += __shfl_xor(dsacc, 16);
  dsacc += __shfl_xor(dsacc, 32);

  const float kss = kssum[bh];
  float fac[4], oinv[4];
#pragma unroll
  for (int jj = 0; jj < 4; ++jj) {
    const int src = sq * 4 + jj;  // lane holding row (w*16 + sq*4 + jj) stats
    const float s_row = __shfl(mxacc, src);
    const float d_row = __shfl(dsacc, src);
    const float f = __expf(s_row) * EPSI;
    fac[jj] = f;
    oinv[jj] = 1.f / (d_row + f * kss);
  }

  const float* csb = ctxsum + bh * DD;
#pragma unroll
  for (int E = 0; E < 4; ++E) {
    const float cse = csb[E * 16 + c];
#pragma unroll
    for (int jj = 0; jj < 4; ++jj) {
      const int row = r0 + w * 16 + sq * 4 + jj;
      out[((size_t)bh * NN + row) * DD + E * 16 + c] =
          (oacc[E][jj] + fac[jj] * cse) * oinv[jj];
    }
  }
}

extern "C" void kernel_launch(void* const* d_in, const int* in_sizes, int n_in,
                              void* d_out, int out_size, void* d_ws, size_t ws_size,
                              hipStream_t stream) {
  const float* Q    = (const float*)d_in[0];
  const float* K    = (const float*)d_in[1];
  const float* V    = (const float*)d_in[2];
  const float* mask = (const float*)d_in[3];
  const float* proj = (const float*)d_in[4];
  float* out = (float*)d_out;

  float* wsf = (float*)d_ws;
  float* stabk  = wsf;                         // 32
  float* ksum   = wsf + 32;                    // 8192
  float* kssum  = wsf + 8224;                  // 32
  float* ctxsum = wsf + 8256;                  // 2048
  unsigned short* projH = (unsigned short*)(wsf + 10304);   // 16384 shorts
  unsigned short* projL = (unsigned short*)(wsf + 18496);   // 16384 shorts
  unsigned short* ctxTH = (unsigned short*)(wsf + 26688);   // 524288 shorts
  unsigned short* ctxTL = (unsigned short*)(wsf + 288832);  // 524288 shorts
  float* Vs   = wsf + 550976;                  // 2048  (memset region start)
  float* ksE  = wsf + 553024;                  // 8192
  float* ctxE = wsf + 561216;                  // 524288; end 1085504 fl (~4.3MB)

  hipMemsetAsync(wsf + 550976, 0, (2048 + 8192 + 524288) * sizeof(float), stream);

  prep_kernel<<<64, 256, 0, stream>>>(proj, projH, projL, stabk);
  vsum_kernel<<<dim3(32, BH), 256, 0, stream>>>(V, mask, Vs);
  kside_kernel<<<dim3(16, BH), 256, 0, stream>>>(K, V, mask, proj, stabk, ksE, ctxE);
  fixup_kernel<<<BH, 256, 0, stream>>>(stabk, Vs, ksE, ctxE, ksum, kssum, ctxsum, ctxTH, ctxTL);
  out_kernel<<<dim3(64, BH), 256, 0, stream>>>(Q, projH, projL, ksum, ctxTH, ctxTL, kssum, ctxsum, out);
}